// Round 6
// baseline (205.164 us; speedup 1.0000x reference)
//
#include <hip/hip_runtime.h>

// BinaryLSTMCell fused kernel v5b for MI355X (gfx950).
// B=65536, D=256, U=256. out = [h_new | h_new | c_new], f32.
//
// v1-v4 law: wall ~ 16.6k-cyc/block-step / resident-blocks; stall is intra-step
// serial chain + correlated phases across blocks. v5: pipelined step (reads
// first, convert under MFMA, W j0 full-step lookahead, j1 under j0-MFMAs),
// block phase-stagger to decorrelate, setprio around MFMA, pkrtz/med3 VALU diet.
// v5b: fix cvt_pkrtz result type (__fp16 ext_vector, not _Float16).

#define NB 65536

typedef _Float16 f16x8 __attribute__((ext_vector_type(8)));
typedef __fp16 fp16x2 __attribute__((ext_vector_type(2)));
typedef float f32x16 __attribute__((ext_vector_type(16)));

__device__ __forceinline__ float htanh(float x) {
  return __builtin_amdgcn_fmed3f(x, -1.0f, 1.0f);
}

// ---------------------------------------------------------------------------
// prep: binarize both weight matrices into 1024 pre-built MFMA B-fragments.
// fragid = ((k16*2 + side)*8 + u32)*4 + gate, 1KB each:
//   lane l holds 16B: n = gate*256 + u32*32 + (l&31), k = k16*16 + (l>>5)*8 + e.
// ---------------------------------------------------------------------------
__global__ void prep_w(const float* __restrict__ Kf, const float* __restrict__ RKf,
                       unsigned short* __restrict__ wfrag) {
  __shared__ unsigned short sgn[32][72];
  const int b = blockIdx.x;            // 256 blocks
  const int side = b >> 7, kt = (b >> 4) & 7, nt = b & 15;
  const float* M = side ? RKf : Kf;
  const int t = threadIdx.x;

  {  // load 32k x 64n tile, coalesced, store signs
    const int k = t >> 3, n8 = (t & 7) << 3;
    const float* p = M + (kt * 32 + k) * 1024 + nt * 64 + n8;
    float4 v0 = *(const float4*)p;
    float4 v1 = *(const float4*)(p + 4);
    float xs[8] = {v0.x, v0.y, v0.z, v0.w, v1.x, v1.y, v1.z, v1.w};
#pragma unroll
    for (int i = 0; i < 8; ++i)
      sgn[k][n8 + i] = (xs[i] >= 0.f) ? 0x3C00u : 0xBC00u;
  }
  __syncthreads();

  const int fl = t >> 6, l = t & 63;
  const int j = fl >> 1, uhh = fl & 1;
  const int nloc = uhh * 32 + (l & 31);
  const int kloc = j * 16 + (l >> 5) * 8;
  unsigned short o[8];
#pragma unroll
  for (int e = 0; e < 8; ++e) o[e] = sgn[kloc + e][nloc];
  const int ng = nt * 64 + nloc;
  const int gate = ng >> 8, u32 = (ng >> 5) & 7;
  const int k16 = kt * 2 + j;
  const int fragid = ((k16 * 2 + side) * 8 + u32) * 4 + gate;
  uint4 ov;
  ov.x = (unsigned)o[0] | ((unsigned)o[1] << 16);
  ov.y = (unsigned)o[2] | ((unsigned)o[3] << 16);
  ov.z = (unsigned)o[4] | ((unsigned)o[5] << 16);
  ov.w = (unsigned)o[6] | ((unsigned)o[7] << 16);
  *(uint4*)((char*)wfrag + fragid * 1024 + l * 16) = ov;
}

// ---------------------------------------------------------------------------
// main: 256 thr (4 waves: side sw x u32 wu). Block tile m32 x u64, both sides.
// K loop: 8 staggered steps of 32 f32-k; A dbuf LDS k-major f16 hi|lo; W L2.
// ---------------------------------------------------------------------------
__global__ __launch_bounds__(256, 3)
void blstm_main(const float* __restrict__ xin, const float* __restrict__ hin,
                const float* __restrict__ cin, const unsigned short* __restrict__ wfrag,
                float* __restrict__ out) {
  __shared__ char smem[32768];   // A: [0,16896); epilogue exchange aliases

  const int bid = blockIdx.x;
  const int swz = (bid & 7) * 1024 + (bid >> 3);   // XCD swizzle, 8192 % 8 == 0
  const int m0 = (swz >> 2) << 5;
  const int ub = swz & 3;
  const int phase = (bid >> 3) & 7;                // decorrelate co-resident blocks

  const int tid = threadIdx.x;
  const int lane = tid & 63;
  const int w = tid >> 6;
  const int wu = w & 1, sw = w >> 1;
  const int l31 = lane & 31, lh = lane >> 5;

  // ---- A staging role (wave-uniform side) ----
  const int sSide = tid >> 7;
  const int sRow = (tid & 127) >> 2;
  const int sQ = tid & 3;
  const float* aPtr = (sSide ? hin : xin) + (m0 + sRow) * 256 + sQ * 8;
  char* const aWr = smem + sSide * 4224 + sQ * 528 + sRow * 16;   // lo at +2112
  const char* const aRd = smem + sw * 4224 + lh * 528 + l31 * 16;

  // ---- W fragment base: byte = (sw*8 + ub*2 + wu)*4096 + lane*16 ----
  const char* const wqB = (const char*)wfrag + ((sw * 8 + ub * 2 + wu) << 12) + lane * 16;
  // per k16 (=s*2+j): +k16*65536; per gate: +g*1024

  f32x16 acc[4] = {};
  f16x8 wa0, wa1, wa2, wa3;            // W(s, j0), full-step lookahead
  float4 a0, a1;

#define CONVERT_WRITE(WRBUF) do {                                           \
    float x0_ = a0.x, x1_ = a0.y, x2_ = a0.z, x3_ = a0.w;                   \
    float x4_ = a1.x, x5_ = a1.y, x6_ = a1.z, x7_ = a1.w;                   \
    if (sSide) {                                                            \
      x0_ = htanh(x0_); x1_ = htanh(x1_); x2_ = htanh(x2_); x3_ = htanh(x3_); \
      x4_ = htanh(x4_); x5_ = htanh(x5_); x6_ = htanh(x6_); x7_ = htanh(x7_); \
    }                                                                       \
    fp16x2 h01_ = __builtin_amdgcn_cvt_pkrtz(x0_, x1_);                     \
    fp16x2 h23_ = __builtin_amdgcn_cvt_pkrtz(x2_, x3_);                     \
    fp16x2 h45_ = __builtin_amdgcn_cvt_pkrtz(x4_, x5_);                     \
    fp16x2 h67_ = __builtin_amdgcn_cvt_pkrtz(x6_, x7_);                     \
    fp16x2 l01_ = __builtin_amdgcn_cvt_pkrtz(x0_ - (float)h01_[0], x1_ - (float)h01_[1]); \
    fp16x2 l23_ = __builtin_amdgcn_cvt_pkrtz(x2_ - (float)h23_[0], x3_ - (float)h23_[1]); \
    fp16x2 l45_ = __builtin_amdgcn_cvt_pkrtz(x4_ - (float)h45_[0], x5_ - (float)h45_[1]); \
    fp16x2 l67_ = __builtin_amdgcn_cvt_pkrtz(x6_ - (float)h67_[0], x7_ - (float)h67_[1]); \
    uint4 H_, L_;                                                           \
    H_.x = __builtin_bit_cast(unsigned, h01_); H_.y = __builtin_bit_cast(unsigned, h23_); \
    H_.z = __builtin_bit_cast(unsigned, h45_); H_.w = __builtin_bit_cast(unsigned, h67_); \
    L_.x = __builtin_bit_cast(unsigned, l01_); L_.y = __builtin_bit_cast(unsigned, l23_); \
    L_.z = __builtin_bit_cast(unsigned, l45_); L_.w = __builtin_bit_cast(unsigned, l67_); \
    *(uint4*)(WRBUF) = H_;                                                  \
    *(uint4*)((WRBUF) + 2112) = L_;                                         \
  } while (0)

#define MFMA4(AF, W0, W1, W2, W3) do {                                      \
    acc[0] = __builtin_amdgcn_mfma_f32_32x32x16_f16(AF, W0, acc[0], 0, 0, 0); \
    acc[1] = __builtin_amdgcn_mfma_f32_32x32x16_f16(AF, W1, acc[1], 0, 0, 0); \
    acc[2] = __builtin_amdgcn_mfma_f32_32x32x16_f16(AF, W2, acc[2], 0, 0, 0); \
    acc[3] = __builtin_amdgcn_mfma_f32_32x32x16_f16(AF, W3, acc[3], 0, 0, 0); \
  } while (0)

  // ---- prologue: stage A(s0) into buf0; preload wfA = W(s0,j0); A(s1) in regs ----
  {
    const int s0 = phase;
    a0 = *(const float4*)(aPtr + s0 * 32);
    a1 = *(const float4*)(aPtr + s0 * 32 + 4);
    const char* wp0 = wqB + s0 * 131072;
    wa0 = *(const f16x8*)(wp0);
    wa1 = *(const f16x8*)(wp0 + 1024);
    wa2 = *(const f16x8*)(wp0 + 2048);
    wa3 = *(const f16x8*)(wp0 + 3072);
    CONVERT_WRITE(aWr);
    const int s1 = (phase + 1) & 7;
    a0 = *(const float4*)(aPtr + s1 * 32);
    a1 = *(const float4*)(aPtr + s1 * 32 + 4);
    asm volatile("s_waitcnt lgkmcnt(0)\n\ts_barrier" ::: "memory");
  }

#define STEP(S) do {                                                        \
    const int s_ = ((S) + phase) & 7;                                       \
    const char* rd_ = aRd + ((S) & 1) * 8448;                               \
    f16x8 ah0_ = *(const f16x8*)(rd_);                                      \
    f16x8 al0_ = *(const f16x8*)(rd_ + 2112);                               \
    f16x8 ah1_ = *(const f16x8*)(rd_ + 1056);                               \
    f16x8 al1_ = *(const f16x8*)(rd_ + 3168);                               \
    /* W(s, j1): issue now, first use after j0's 8 MFMAs */                 \
    const char* wpB_ = wqB + s_ * 131072 + 65536;                           \
    f16x8 wb0_ = *(const f16x8*)(wpB_);                                     \
    f16x8 wb1_ = *(const f16x8*)(wpB_ + 1024);                              \
    f16x8 wb2_ = *(const f16x8*)(wpB_ + 2048);                              \
    f16x8 wb3_ = *(const f16x8*)(wpB_ + 3072);                              \
    /* convert A(s+1) (regs) -> buf[(S+1)&1]; then refill aCur with A(s+2) */ \
    if ((S) < 7) CONVERT_WRITE(aWr + (((S) + 1) & 1) * 8448);               \
    if ((S) < 6) {                                                          \
      const int s2_ = ((S) + 2 + phase) & 7;                                \
      a0 = *(const float4*)(aPtr + s2_ * 32);                               \
      a1 = *(const float4*)(aPtr + s2_ * 32 + 4);                           \
    }                                                                       \
    __builtin_amdgcn_s_setprio(1);                                          \
    MFMA4(ah0_, wa0, wa1, wa2, wa3);                                        \
    MFMA4(al0_, wa0, wa1, wa2, wa3);                                        \
    if ((S) < 7) {  /* W(s+1, j0) for next step (full-step lookahead) */    \
      const char* wpN_ = wqB + ((((S) + 1 + phase) & 7)) * 131072;          \
      wa0 = *(const f16x8*)(wpN_);                                          \
      wa1 = *(const f16x8*)(wpN_ + 1024);                                   \
      wa2 = *(const f16x8*)(wpN_ + 2048);                                   \
      wa3 = *(const f16x8*)(wpN_ + 3072);                                   \
    }                                                                       \
    MFMA4(ah1_, wb0_, wb1_, wb2_, wb3_);                                    \
    MFMA4(al1_, wb0_, wb1_, wb2_, wb3_);                                    \
    __builtin_amdgcn_s_setprio(0);                                          \
    asm volatile("s_waitcnt lgkmcnt(0)\n\ts_barrier" ::: "memory");         \
  } while (0)

  STEP(0); STEP(1); STEP(2); STEP(3);
  STEP(4); STEP(5); STEP(6); STEP(7);
#undef STEP
#undef MFMA4
#undef CONVERT_WRITE

  // ---- epilogue ----
  // C/D layout (verified): col = lane&31, row = (reg&3) + 8*(reg>>2) + 4*(lane>>5)
  __syncthreads();   // all K-loop LDS traffic done before aliasing A region
  float* ex = (float*)(smem + wu * 16384);  // [gate4][quad4][64 lanes x 16B]

  if (sw == 1) {     // r-waves dump raw acc quads
#pragma unroll
    for (int g = 0; g < 4; ++g)
#pragma unroll
      for (int q = 0; q < 4; ++q) {
        float4 v;
        v.x = acc[g][q * 4 + 0]; v.y = acc[g][q * 4 + 1];
        v.z = acc[g][q * 4 + 2]; v.w = acc[g][q * 4 + 3];
        *(float4*)((char*)ex + (g * 4 + q) * 1024 + lane * 16) = v;
      }
  }
  __syncthreads();
  if (sw == 0) {     // x-waves combine gates and write out
    const int gu = ub * 64 + wu * 32 + l31;
#pragma unroll
    for (int q = 0; q < 4; ++q) {
      float4 ri = *(const float4*)((const char*)ex + (0 * 4 + q) * 1024 + lane * 16);
      float4 rf = *(const float4*)((const char*)ex + (1 * 4 + q) * 1024 + lane * 16);
      float4 rc = *(const float4*)((const char*)ex + (2 * 4 + q) * 1024 + lane * 16);
      float4 ro = *(const float4*)((const char*)ex + (3 * 4 + q) * 1024 + lane * 16);
#pragma unroll
      for (int t = 0; t < 4; ++t) {
        const int r = q * 4 + t;
        const int row = t + q * 8 + lh * 4;
        const int grow = m0 + row;
        const float xi = htanh(acc[0][r]);
        const float xf = htanh(acc[1][r]);
        const float xc = htanh(acc[2][r]);
        const float xo = htanh(acc[3][r]);
        const float riv = ((const float*)&ri)[t];
        const float rfv = ((const float*)&rf)[t];
        const float rcv = ((const float*)&rc)[t];
        const float rov = ((const float*)&ro)[t];
        // reference gate crossing: f = ht(x_i + r_f), i = ht(x_f + r_i)
        const float fg   = htanh(xi + rfv);
        const float ig   = htanh(xf + riv);
        const float cand = htanh(xc + rcv);
        const float og   = htanh(xo + rov);
        const float ct = htanh(cin[grow * 256 + gu]);
        const float cn = fg * ct + ig * cand;
        const float hn = htanh(og * htanh(cn));
        const int o1 = grow * 256 + gu;
        out[o1] = hn;
        out[NB * 256 + o1] = hn;
        out[2 * NB * 256 + o1] = cn;
      }
    }
  }
}

extern "C" void kernel_launch(void* const* d_in, const int* in_sizes, int n_in,
                              void* d_out, int out_size, void* d_ws, size_t ws_size,
                              hipStream_t stream) {
  const float* xin = (const float*)d_in[0];
  const float* hin = (const float*)d_in[1];
  const float* cin = (const float*)d_in[2];
  const float* kf  = (const float*)d_in[3];
  const float* rkf = (const float*)d_in[4];
  float* out = (float*)d_out;

  unsigned short* wfrag = (unsigned short*)d_ws;    // 1024 frags x 1KB = 1MB

  prep_w<<<256, 256, 0, stream>>>(kf, rkf, wfrag);
  blstm_main<<<8192, 256, 0, stream>>>(xin, hin, cin, wfrag, out);
}